// Round 1
// baseline (412.289 us; speedup 1.0000x reference)
//
#include <hip/hip_runtime.h>
#include <hip/hip_bf16.h>

#define N_PTS 800000
#define KVOL 27
#define NPAIR 14        // 27 taps -> 14 pairs (last pair: tap 26 + zero-pad)
#define NHEADS 4
#define NT (N_PTS / 16) // 50000 16-point tiles

typedef __attribute__((ext_vector_type(8))) short short8;
typedef __attribute__((ext_vector_type(4))) float f32x4;

__device__ inline short f2bf(float x) {
    __hip_bfloat16 h = __float2bfloat16(x);
    short s;
    __builtin_memcpy(&s, &h, 2);
    return s;
}

__global__ __launch_bounds__(512, 4) void mh_sparse_conv(
        const float* __restrict__ feats,   // [N_PTS][64]
        const float* __restrict__ W,       // [27][4][16][16]
        const int*   __restrict__ kmap,    // [27][N_PTS]
        float*       __restrict__ out) {   // [N_PTS][64]

    // ---- stage packed B fragments (bf16) into LDS ----
    // layout: bsh[((t*4 + h)*64 + lane)*8 + j]
    __shared__ short bsh[NPAIR * NHEADS * 64 * 8];   // 57344 B
    const int tid = threadIdx.x;
    for (int e = tid; e < NPAIR * NHEADS * 64 * 8; e += 512) {
        const int j    = e & 7;
        const int ln   = (e >> 3) & 63;
        const int h    = (e >> 9) & 3;
        const int t    = e >> 11;
        const int gg   = ln >> 4;
        const int d    = ln & 15;
        const int kl   = gg >> 1;
        const int c    = ((gg & 1) << 3) + j;
        const int tap  = 2 * t + kl;
        const float w  = (tap < KVOL) ? W[((tap * NHEADS + h) * 16 + c) * 16 + d] : 0.0f;
        bsh[e] = f2bf(w);
    }
    __syncthreads();

    const int lane = tid & 63;
    const int wid  = tid >> 6;                 // 0..7
    const int m    = lane & 15;                // point row within tile (A row)
    const int gg   = lane >> 4;                // lane group 0..3
    const int kl   = gg >> 1;                  // tap-within-pair
    const int ch   = (gg & 1) << 3;            // channel offset within head (0 or 8)
    const int gw   = blockIdx.x * 8 + wid;     // global wave id
    const int nw   = gridDim.x * 8;

    for (int tile = gw; tile < NT; tile += nw) {
        const int p = tile * 16 + m;
        f32x4 acc0 = {0.f,0.f,0.f,0.f};
        f32x4 acc1 = {0.f,0.f,0.f,0.f};
        f32x4 acc2 = {0.f,0.f,0.f,0.f};
        f32x4 acc3 = {0.f,0.f,0.f,0.f};

        #pragma unroll
        for (int t = 0; t < NPAIR; ++t) {
            const int tap = 2 * t + kl;
            int idx = -1;
            if (tap < KVOL) idx = kmap[tap * N_PTS + p];

            if (__ballot(idx >= 0)) {
                short8 a0 = {0,0,0,0,0,0,0,0};
                short8 a1 = {0,0,0,0,0,0,0,0};
                short8 a2 = {0,0,0,0,0,0,0,0};
                short8 a3 = {0,0,0,0,0,0,0,0};
                if (idx >= 0) {
                    const float* fr = feats + (size_t)idx * 64 + ch;
                    const float4 x0 = *(const float4*)(fr +  0);
                    const float4 x1 = *(const float4*)(fr +  4);
                    const float4 x2 = *(const float4*)(fr + 16);
                    const float4 x3 = *(const float4*)(fr + 20);
                    const float4 x4 = *(const float4*)(fr + 32);
                    const float4 x5 = *(const float4*)(fr + 36);
                    const float4 x6 = *(const float4*)(fr + 48);
                    const float4 x7 = *(const float4*)(fr + 52);
                    a0 = (short8){f2bf(x0.x), f2bf(x0.y), f2bf(x0.z), f2bf(x0.w),
                                  f2bf(x1.x), f2bf(x1.y), f2bf(x1.z), f2bf(x1.w)};
                    a1 = (short8){f2bf(x2.x), f2bf(x2.y), f2bf(x2.z), f2bf(x2.w),
                                  f2bf(x3.x), f2bf(x3.y), f2bf(x3.z), f2bf(x3.w)};
                    a2 = (short8){f2bf(x4.x), f2bf(x4.y), f2bf(x4.z), f2bf(x4.w),
                                  f2bf(x5.x), f2bf(x5.y), f2bf(x5.z), f2bf(x5.w)};
                    a3 = (short8){f2bf(x6.x), f2bf(x6.y), f2bf(x6.z), f2bf(x6.w),
                                  f2bf(x7.x), f2bf(x7.y), f2bf(x7.z), f2bf(x7.w)};
                }
                const short8* bp = (const short8*)(bsh + ((size_t)t * 4 * 64 + lane) * 8);
                const short8 b0 = bp[0];
                const short8 b1 = bp[64];
                const short8 b2 = bp[128];
                const short8 b3 = bp[192];
                acc0 = __builtin_amdgcn_mfma_f32_16x16x32_bf16(a0, b0, acc0, 0, 0, 0);
                acc1 = __builtin_amdgcn_mfma_f32_16x16x32_bf16(a1, b1, acc1, 0, 0, 0);
                acc2 = __builtin_amdgcn_mfma_f32_16x16x32_bf16(a2, b2, acc2, 0, 0, 0);
                acc3 = __builtin_amdgcn_mfma_f32_16x16x32_bf16(a3, b3, acc3, 0, 0, 0);
            }
        }

        // ---- store: D layout col = lane&15, row = (lane>>4)*4 + r ----
        const int col = lane & 15;
        const int r0  = tile * 16 + (lane >> 4) * 4;
        #pragma unroll
        for (int r = 0; r < 4; ++r) {
            const size_t ro = (size_t)(r0 + r) * 64;
            out[ro +  0 + col] = acc0[r];
            out[ro + 16 + col] = acc1[r];
            out[ro + 32 + col] = acc2[r];
            out[ro + 48 + col] = acc3[r];
        }
    }
}

extern "C" void kernel_launch(void* const* d_in, const int* in_sizes, int n_in,
                              void* d_out, int out_size, void* d_ws, size_t ws_size,
                              hipStream_t stream) {
    const float* feats = (const float*)d_in[0];
    const float* W     = (const float*)d_in[1];
    const int*   kmap  = (const int*)d_in[2];
    float*       out   = (float*)d_out;

    dim3 grid(1024), block(512);
    hipLaunchKernelGGL(mh_sparse_conv, grid, block, 0, stream, feats, W, kmap, out);
}